// Round 3
// baseline (626.337 us; speedup 1.0000x reference)
//
#include <hip/hip_runtime.h>
#include <cstdint>

#define CTX 512
#define HID 2048
#define NCELL 4096
#define M_TOT 32768          // 8 * 4096 rows

typedef __bf16 bf16;
typedef __attribute__((ext_vector_type(8))) __bf16 bf16x8;
typedef __attribute__((ext_vector_type(4))) float f32x4;

// Fallback scratch if ws_size is too small (preferred path uses d_ws).
__device__ __align__(16) unsigned short g_agg[(size_t)M_TOT * CTX];
__device__ __align__(16) unsigned short g_WT[(size_t)HID * CTX];
__device__ int g_flag;

__device__ __forceinline__ float bf2f(unsigned short u) {
  union { unsigned int i; float f; } c; c.i = ((unsigned int)u) << 16; return c.f;
}
__device__ __forceinline__ unsigned short f2bf(float f) {
  union { float f; unsigned int i; } c; c.f = f;
  unsigned int u = c.i;
  u += 0x7fffu + ((u >> 16) & 1u);   // RNE
  return (unsigned short)(u >> 16);
}
__device__ __forceinline__ float lo16(unsigned int w) {
  union { unsigned int i; float f; } c; c.i = w << 16; return c.f;
}
__device__ __forceinline__ float hi16(unsigned int w) {
  union { unsigned int i; float f; } c; c.i = w & 0xffff0000u; return c.f;
}

// ---------------------------------------------------------------------------
// Kernel 0: dtype detector. Genuine bf16 N(0,1) data: exponent field <= ~0x82,
// zero hits. fp32 read as u16 pairs: low halves ~uniform -> ~3% have exp>=0xF8.
// ---------------------------------------------------------------------------
__global__ void detect_dtype(const unsigned short* __restrict__ x, int* flagp) {
  __shared__ int cnt;
  if (threadIdx.x == 0) cnt = 0;
  __syncthreads();
  const uint4 v = ((const uint4*)x)[threadIdx.x];   // 8 u16 per thread, 2048 total
  unsigned int w[4] = {v.x, v.y, v.z, v.w};
  int c = 0;
#pragma unroll
  for (int i = 0; i < 4; ++i) {
    unsigned int lo = w[i] & 0xffffu, hi = w[i] >> 16;
    c += (((lo >> 7) & 0xffu) >= 0xF8u);
    c += (((hi >> 7) & 0xffu) >= 0xF8u);
  }
  atomicAdd(&cnt, c);
  __syncthreads();
  if (threadIdx.x == 0) *flagp = (cnt > 8) ? 1 : 0;   // 1 = fp32 inputs
}

// ---------------------------------------------------------------------------
// Kernel 1: WT[h][c] = W[c][h] as bf16. grid (HID/64, CTX/32), block 256.
// ---------------------------------------------------------------------------
__global__ void transpose_w(const void* __restrict__ Wv,
                            unsigned short* __restrict__ wt,
                            const int* __restrict__ flagp) {
  const int isf32 = *flagp;
  const int t  = threadIdx.x;
  const int h  = blockIdx.x * 64 + (t & 63);
  const int c0 = (blockIdx.y * 4 + (t >> 6)) * 8;
  float e[8];
  if (isf32) {
    const float* Wf = (const float*)Wv;
#pragma unroll
    for (int j = 0; j < 8; ++j) e[j] = Wf[(size_t)(c0 + j) * HID + h];
  } else {
    const unsigned short* Wb = (const unsigned short*)Wv;
#pragma unroll
    for (int j = 0; j < 8; ++j) e[j] = bf2f(Wb[(size_t)(c0 + j) * HID + h]);
  }
  uint4 o;
  o.x = (unsigned int)f2bf(e[0]) | ((unsigned int)f2bf(e[1]) << 16);
  o.y = (unsigned int)f2bf(e[2]) | ((unsigned int)f2bf(e[3]) << 16);
  o.z = (unsigned int)f2bf(e[4]) | ((unsigned int)f2bf(e[5]) << 16);
  o.w = (unsigned int)f2bf(e[6]) | ((unsigned int)f2bf(e[7]) << 16);
  *(uint4*)&wt[(size_t)h * CTX + c0] = o;
}

// ---------------------------------------------------------------------------
// Kernel 2: agg[m][c] = sum_k sim[n,k] * x[b, idx[n,k], c], bf16 out.
// One wave per row m; lane covers 8 c-elems. grid 8192, block 256.
// ---------------------------------------------------------------------------
__global__ void gather_agg_k(const void* __restrict__ xv,
                             const int* __restrict__ nn_idx,
                             const void* __restrict__ simv,
                             unsigned short* __restrict__ agg,
                             const int* __restrict__ flagp) {
  const int isf32 = *flagp;
  const int m    = blockIdx.x * 4 + (threadIdx.x >> 6);
  const int lane = threadIdx.x & 63;
  const int b    = m >> 12;
  const int n    = m & (NCELL - 1);
  const int c0   = lane * 8;

  float a[8] = {0, 0, 0, 0, 0, 0, 0, 0};
  if (isf32) {
    const float* xf = (const float*)xv;
    const float* sf = (const float*)simv;
#pragma unroll
    for (int k = 0; k < 8; ++k) {
      const int   idx = nn_idx[n * 8 + k];
      const float wgt = sf[n * 8 + k];
      const float* p  = xf + ((size_t)(b * NCELL + idx) * CTX + c0);
      const float4 v0 = *(const float4*)p;
      const float4 v1 = *(const float4*)(p + 4);
      a[0] += wgt * v0.x; a[1] += wgt * v0.y; a[2] += wgt * v0.z; a[3] += wgt * v0.w;
      a[4] += wgt * v1.x; a[5] += wgt * v1.y; a[6] += wgt * v1.z; a[7] += wgt * v1.w;
    }
  } else {
    const unsigned short* xb = (const unsigned short*)xv;
    const unsigned short* sb = (const unsigned short*)simv;
#pragma unroll
    for (int k = 0; k < 8; ++k) {
      const int   idx = nn_idx[n * 8 + k];
      const float wgt = bf2f(sb[n * 8 + k]);
      const uint4 v = *(const uint4*)(xb + ((size_t)(b * NCELL + idx) * CTX + c0));
      a[0] += wgt * lo16(v.x); a[1] += wgt * hi16(v.x);
      a[2] += wgt * lo16(v.y); a[3] += wgt * hi16(v.y);
      a[4] += wgt * lo16(v.z); a[5] += wgt * hi16(v.z);
      a[6] += wgt * lo16(v.w); a[7] += wgt * hi16(v.w);
    }
  }
  uint4 o;
  o.x = (unsigned int)f2bf(a[0]) | ((unsigned int)f2bf(a[1]) << 16);
  o.y = (unsigned int)f2bf(a[2]) | ((unsigned int)f2bf(a[3]) << 16);
  o.z = (unsigned int)f2bf(a[4]) | ((unsigned int)f2bf(a[5]) << 16);
  o.w = (unsigned int)f2bf(a[6]) | ((unsigned int)f2bf(a[7]) << 16);
  *(uint4*)&agg[(size_t)m * CTX + c0] = o;
}

// ---------------------------------------------------------------------------
// Kernel 3: C[m][h] = sum_c agg[m][c] * wt[h][c]  (both row-major, K inner)
// 128x128 tile, BK=64, 4 waves x (4x4) 16x16x32 bf16 MFMAs. LDS rows padded
// to 72 elems. grid (HID/128=16, M_TOT/128=256).
// ---------------------------------------------------------------------------
#define LDSTR 72
__global__ __launch_bounds__(256) void gemm_bt(const unsigned short* __restrict__ agg,
                                               const unsigned short* __restrict__ wt,
                                               void* __restrict__ outv,
                                               const int* __restrict__ flagp) {
  __shared__ alignas(16) bf16 As[128 * LDSTR];
  __shared__ alignas(16) bf16 Bs[128 * LDSTR];

  const int tid  = threadIdx.x;
  const int wave = tid >> 6;
  const int lane = tid & 63;
  const int l16  = lane & 15;
  const int quad = lane >> 4;

  const int gn0 = blockIdx.x * 128;
  const int gm0 = blockIdx.y * 128;
  const int wm  = (wave & 1) * 64;
  const int wn  = (wave >> 1) * 64;

  f32x4 acc[4][4] = {};

  const int sr = tid >> 3;        // staging row 0..31 (+i*32)
  const int sc = (tid & 7) * 8;   // 16B chunk

  for (int kt = 0; kt < CTX; kt += 64) {
    uint4 av[4], bv[4];
#pragma unroll
    for (int i = 0; i < 4; ++i) {
      av[i] = *(const uint4*)&agg[(size_t)(gm0 + sr + i * 32) * CTX + kt + sc];
      bv[i] = *(const uint4*)&wt [(size_t)(gn0 + sr + i * 32) * CTX + kt + sc];
    }
    __syncthreads();
#pragma unroll
    for (int i = 0; i < 4; ++i) {
      *(uint4*)&As[(sr + i * 32) * LDSTR + sc] = av[i];
      *(uint4*)&Bs[(sr + i * 32) * LDSTR + sc] = bv[i];
    }
    __syncthreads();

#pragma unroll
    for (int s = 0; s < 2; ++s) {
      bf16x8 af[4], bfr[4];
#pragma unroll
      for (int mi = 0; mi < 4; ++mi)
        af[mi] = *(const bf16x8*)&As[(wm + mi * 16 + l16) * LDSTR + (s * 4 + quad) * 8];
#pragma unroll
      for (int ni = 0; ni < 4; ++ni)
        bfr[ni] = *(const bf16x8*)&Bs[(wn + ni * 16 + l16) * LDSTR + (s * 4 + quad) * 8];
#pragma unroll
      for (int mi = 0; mi < 4; ++mi)
#pragma unroll
        for (int ni = 0; ni < 4; ++ni)
          acc[mi][ni] = __builtin_amdgcn_mfma_f32_16x16x32_bf16(
              af[mi], bfr[ni], acc[mi][ni], 0, 0, 0);
    }
  }

  // C/D layout (m89/m91): col = lane&15, row = quad*4 + reg
  const int isf32 = *flagp;
  if (isf32) {
    float* out = (float*)outv;
#pragma unroll
    for (int mi = 0; mi < 4; ++mi)
#pragma unroll
      for (int r = 0; r < 4; ++r) {
        const size_t row = (size_t)(gm0 + wm + mi * 16 + quad * 4 + r);
#pragma unroll
        for (int ni = 0; ni < 4; ++ni)
          out[row * HID + gn0 + wn + ni * 16 + l16] = acc[mi][ni][r];
      }
  } else {
    unsigned short* out = (unsigned short*)outv;
#pragma unroll
    for (int mi = 0; mi < 4; ++mi)
#pragma unroll
      for (int r = 0; r < 4; ++r) {
        const size_t row = (size_t)(gm0 + wm + mi * 16 + quad * 4 + r);
#pragma unroll
        for (int ni = 0; ni < 4; ++ni)
          out[row * HID + gn0 + wn + ni * 16 + l16] = f2bf(acc[mi][ni][r]);
      }
  }
}

extern "C" void kernel_launch(void* const* d_in, const int* in_sizes, int n_in,
                              void* d_out, int out_size, void* d_ws, size_t ws_size,
                              hipStream_t stream) {
  const void* x   = d_in[0];
  const void* W   = d_in[1];
  const int*  nn  = (const int*)d_in[2];
  const void* sim = d_in[3];

  const size_t wt_bytes  = (size_t)HID * CTX * 2;    // 2 MB
  const size_t agg_bytes = (size_t)M_TOT * CTX * 2;  // 33.5 MB
  const size_t need      = wt_bytes + agg_bytes + 16;

  unsigned short *wt, *agg; int* flagp;
  if (ws_size >= need) {
    wt    = (unsigned short*)d_ws;
    agg   = (unsigned short*)((char*)d_ws + wt_bytes);
    flagp = (int*)((char*)d_ws + wt_bytes + agg_bytes);
  } else {
    void *p0, *p1, *p2;
    hipGetSymbolAddress(&p0, HIP_SYMBOL(g_WT));
    hipGetSymbolAddress(&p1, HIP_SYMBOL(g_agg));
    hipGetSymbolAddress(&p2, HIP_SYMBOL(g_flag));
    wt = (unsigned short*)p0; agg = (unsigned short*)p1; flagp = (int*)p2;
  }

  detect_dtype<<<1, 256, 0, stream>>>((const unsigned short*)x, flagp);
  transpose_w<<<dim3(HID / 64, CTX / 32), 256, 0, stream>>>(W, wt, flagp);
  gather_agg_k<<<dim3(M_TOT / 4), 256, 0, stream>>>(x, nn, sim, agg, flagp);
  gemm_bt<<<dim3(HID / 128, M_TOT / 128), 256, 0, stream>>>(agg, wt, d_out, flagp);
}